// Round 10
// baseline (248.927 us; speedup 1.0000x reference)
//
#include <hip/hip_runtime.h>
#include <hip/hip_cooperative_groups.h>
#include <stdint.h>

// Problem dims (fixed by the reference)
#define NB   8192
#define NZ   10
#define CIN  512
#define COUT 512
#define MM   3
#define ALPHA 0.04419417382415922f   // 1/sqrt(512)

#define ROWS_TOTAL (NB * MM)          // 24576 GEMM rows (pos,d) d-fastest
#define BM 256
#define BN 256
#define BK 32
#define NKT (CIN / BK)                // 16 K-tiles
#define MAX_MT (ROWS_TOTAL / BM + NZ) // 106
#define NYB (COUT / BN)               // 2
#define NWG (MAX_MT * NYB)            // 212 blocks (1/CU co-resident)
#define NGRP 32                       // fallback histogram groups
#define DYN_LDS (3 * 2 * 256 * BK * 2)   // 96 KB: 3-slot ring [A 16K | B 16K]

typedef short bf16x8 __attribute__((ext_vector_type(8)));
typedef float f32x4  __attribute__((ext_vector_type(4)));

__device__ __forceinline__ uint16_t f2bf(float f) {
    union { float f; uint32_t i; } v; v.f = f;
    uint32_t x = v.i;
    x += 0x7fffu + ((x >> 16) & 1u);   // RNE
    return (uint16_t)(x >> 16);
}
__device__ __forceinline__ uint32_t pack2(float a, float b) {
    return (uint32_t)f2bf(a) | ((uint32_t)f2bf(b) << 16);
}
__device__ __forceinline__ void async16(const void* g, void* l) {
    __builtin_amdgcn_global_load_lds((const uint32_t*)g, (uint32_t*)l, 16, 0, 0);
}

// ============================================================================
// R10: ONE cooperative kernel. Evidence: total-minus-gemm ~105us constant
// across all rounds while front-end kernels sum to ~30us -> inter-dispatch
// overhead (launch + cache-flush packets + DVFS ramp) dominates. R7's
// counter-evidence was confounded (32x-redundant scalar decode was its long
// pole). Phases:
//   A1: decode (1 thread/node, atomic cnt) || pack_w || pack_tn (node-order)
//   grid.sync
//   A2: per-block 10-elem scan (redundant, LDS) + place via atomic cursors
//       (segment order is free: epilogue scatters by node)
//   grid.sync
//   B:  R9 256x256 8-wave phase-split GEMM; A gathered from node-order ttn
//       via sorted (R7-proven mechanism), 3-slot ring, counted vmcnt.
// meta[]: cnt[0..9], cursor[16..25] — zeroed by hipMemsetAsync pre-launch.
// ============================================================================
__global__ __launch_bounds__(512, 2)
void fused_kernel(const float* __restrict__ t, const float* __restrict__ attrs,
                  const float* __restrict__ w, float* __restrict__ out,
                  int* __restrict__ sorted, int* __restrict__ meta,
                  ushort* __restrict__ wt, ushort* __restrict__ ttn) {
    extern __shared__ __align__(16) ushort smem[];   // 96 KB ring
    __shared__ int spos[96];
    __shared__ int loff[NZ + 1], ltoff[NZ + 1];

    cooperative_groups::grid_group grid = cooperative_groups::this_grid();
    const int bid = blockIdx.x, tid = threadIdx.x;
    const int gtid = bid * 512 + tid;              // 0..108543
    const int w8 = tid >> 6, L = tid & 63;

    // ---- A1a: decode own node (blocks 0..15 only), device-scope count
    int mys = 0;
    if (gtid < NB) {
        const float* a = attrs + (size_t)gtid * NZ;
        #pragma unroll
        for (int z = 0; z < NZ; z++) if (a[z] > 0.5f) mys = z;
        atomicAdd(&meta[mys], 1);
    }
    // ---- A1b: pack_w, grid-stride, 8 elems/task (coalesced)
    for (int i = gtid; i < NZ * COUT * CIN / 8; i += NWG * 512) {
        const float4* src = (const float4*)(w + (size_t)i * 8);
        float4 a = src[0], b = src[1];
        uint4 o;
        o.x = pack2(a.x, a.y); o.y = pack2(a.z, a.w);
        o.z = pack2(b.x, b.y); o.w = pack2(b.z, b.w);
        *(uint4*)(wt + (size_t)i * 8) = o;
    }
    // ---- A1c: pack_tn, wave-per-node, NODE order (no sorted dependency)
    for (int node = bid * 8 + w8; node < NB; node += NWG * 8) {
        const float4* src = (const float4*)(t + (size_t)node * (CIN * MM) + L * 24);
        float4 f[6];
        #pragma unroll
        for (int i = 0; i < 6; i++) f[i] = src[i];
        const float* v = (const float*)f;          // v[c_local*3 + d]
        #pragma unroll
        for (int d = 0; d < MM; d++) {
            uint4 o;
            o.x = pack2(v[d],      v[3 + d]);
            o.y = pack2(v[6 + d],  v[9 + d]);
            o.z = pack2(v[12 + d], v[15 + d]);
            o.w = pack2(v[18 + d], v[21 + d]);
            *(uint4*)&ttn[(size_t)(3 * node + d) * CIN + L * 8] = o;
        }
    }

    grid.sync();   // cnt final; ttn/wt written (device fence + barrier)

    // ---- A2: per-block redundant scan (atomic reads bypass stale caches)
    if (tid == 0) {
        int off = 0, toff = 0;
        for (int z = 0; z < NZ; z++) {
            const int c = atomicAdd(&meta[z], 0);
            loff[z] = off; ltoff[z] = toff;
            off += c;
            toff += (3 * c + BM - 1) / BM;
        }
        loff[NZ] = off; ltoff[NZ] = toff;
    }
    __syncthreads();
    if (gtid < NB) {
        const int p = loff[mys] + atomicAdd(&meta[16 + mys], 1);
        sorted[p] = gtid;
    }

    grid.sync();   // sorted final

    // ================= B: GEMM (R9 structure) ==============================
    // m204 bijective XCD swizzle for NWG=212 (q=26, r=4), y-fastest decode
    const int xcd = bid & 7, ii = bid >> 3;
    const int wg = (xcd < 4 ? xcd * 27 : 108 + (xcd - 4) * 26) + ii;
    const int tz = wg >> 1;
    const int Cbase = (wg & 1) * BN;

    if (tz >= ltoff[NZ]) return;                   // after last grid.sync: safe
    int z = 0;
    #pragma unroll
    for (int i = 1; i < NZ; i++) if (ltoff[i] <= tz) z = i;

    const int row_base = 3 * loff[z] + (tz - ltoff[z]) * BM;
    const int row_end  = 3 * loff[z + 1];
    const int pos0     = row_base / 3;

    if (tid < 96) spos[tid] = sorted[min(pos0 + tid, NB - 1)];

    // staging: wave w8 covers local rows [w8*16, w8*16+16) and +128.
    // A gathered from node-order ttn: row R -> 3*sorted[R/3] + R%3 (clamped;
    // tail rows load valid-but-unused data, guarded out in epilogue).
    // chunk-XOR source swizzle cs (R4/R5-verified ~0 conflicts).
    const int lr16 = w8 * 16 + (L >> 2);
    const int cs   = (L & 3) ^ ((L >> 3) & 3);
    const int R0 = row_base + lr16, R1 = R0 + 128;
    const int pA0 = R0 / 3, dA0 = R0 - 3 * pA0;
    const int pA1 = R1 / 3, dA1 = R1 - 3 * pA1;
    const int nA0 = sorted[min(pA0, NB - 1)];
    const int nA1 = sorted[min(pA1, NB - 1)];
    const ushort* gA0 = ttn + (size_t)(3 * nA0 + dA0) * CIN + cs * 8;
    const ushort* gA1 = ttn + (size_t)(3 * nA1 + dA1) * CIN + cs * 8;
    const size_t boff = ((size_t)z * COUT + Cbase + lr16) * CIN + cs * 8;

#define ASLOT(s) (smem + (s) * 16384)
#define BSLOT(s) (smem + (s) * 16384 + 8192)
#define FSTAGE_A(s, kt) do {                                                  \
        async16(gA0 + (kt) * BK, ASLOT(s) + w8 * 512);                        \
        async16(gA1 + (kt) * BK, ASLOT(s) + 4096 + w8 * 512);                 \
    } while (0)
#define FSTAGE_B(s, kt) do {                                                  \
        async16(wt + boff + (kt) * BK, BSLOT(s) + w8 * 512);                  \
        async16(wt + boff + (size_t)128 * CIN + (kt) * BK,                    \
                BSLOT(s) + 4096 + w8 * 512);                                  \
    } while (0)

    const int wm = w8 & 1, wn = w8 >> 1;
    const int q = L >> 4, mr = L & 15;
    const int qs = (q ^ ((mr >> 1) & 3)) * 8;

    f32x4 acc[8][4];
    #pragma unroll
    for (int i = 0; i < 8; i++)
        #pragma unroll
        for (int j = 0; j < 4; j++) acc[i][j] = (f32x4){0.f, 0.f, 0.f, 0.f};

    FSTAGE_A(0, 0); FSTAGE_B(0, 0);
    FSTAGE_A(1, 1); FSTAGE_B(1, 1);

    int cur = 0, stg = 2;
    for (int kt = 0; kt < NKT; kt++) {
        if (kt + 1 < NKT) {
            asm volatile("s_waitcnt vmcnt(4)" ::: "memory");
        } else {
            asm volatile("s_waitcnt vmcnt(0)" ::: "memory");
        }
        asm volatile("s_barrier" ::: "memory");
        if (kt + 2 < NKT) FSTAGE_A(stg, kt + 2);

        const ushort* Ab = ASLOT(cur);
        const ushort* Bb = BSLOT(cur);
        bf16x8 af[4], bf[4];
        #pragma unroll
        for (int am = 0; am < 4; am++)
            af[am] = *(const bf16x8*)(Ab + (wm * 128 + am * 16 + mr) * 32 + qs);
        #pragma unroll
        for (int bn = 0; bn < 4; bn++)
            bf[bn] = *(const bf16x8*)(Bb + (wn * 64 + bn * 16 + mr) * 32 + qs);
        __builtin_amdgcn_s_setprio(1);
        #pragma unroll
        for (int am = 0; am < 4; am++)
            #pragma unroll
            for (int bn = 0; bn < 4; bn++)
                acc[am][bn] = __builtin_amdgcn_mfma_f32_16x16x32_bf16(
                    af[am], bf[bn], acc[am][bn], 0, 0, 0);
        __builtin_amdgcn_s_setprio(0);

        asm volatile("s_barrier" ::: "memory");
        if (kt + 2 < NKT) FSTAGE_B(stg, kt + 2);

        bf16x8 ag[4];
        #pragma unroll
        for (int am = 0; am < 4; am++)
            ag[am] = *(const bf16x8*)(Ab + (wm * 128 + (am + 4) * 16 + mr) * 32 + qs);
        __builtin_amdgcn_s_setprio(1);
        #pragma unroll
        for (int am = 0; am < 4; am++)
            #pragma unroll
            for (int bn = 0; bn < 4; bn++)
                acc[am + 4][bn] = __builtin_amdgcn_mfma_f32_16x16x32_bf16(
                    ag[am], bf[bn], acc[am + 4][bn], 0, 0, 0);
        __builtin_amdgcn_s_setprio(0);

        cur = (cur == 2) ? 0 : cur + 1;
        stg = (stg == 2) ? 0 : stg + 1;
    }
#undef FSTAGE_A
#undef FSTAGE_B

    // ---- epilogue: acc -> ebuf [16 pos][BN][3] -> full-line global stores
    float* ebuf = (float*)smem;
    #pragma unroll
    for (int ch = 0; ch < 6; ch++) {
        __syncthreads();
        const int pbase = pos0 + ch * 16;
        #pragma unroll
        for (int am = 0; am < 8; am++) {
            #pragma unroll
            for (int r = 0; r < 4; r++) {
                const int Rg = row_base + wm * 128 + am * 16 + q * 4 + r;
                const int pos = Rg / 3;
                const int d = Rg - 3 * pos;
                const int lp = pos - pbase;
                if (lp >= 0 && lp < 16 && Rg < row_end) {
                    #pragma unroll
                    for (int bn = 0; bn < 4; bn++) {
                        const int c = wn * 64 + bn * 16 + mr;
                        ebuf[(lp * BN + c) * 3 + d] = ALPHA * acc[am][bn][r];
                    }
                }
            }
        }
        __syncthreads();
        #pragma unroll 4
        for (int j = 0; j < 24; j++) {
            const int idx = j * 512 + tid;
            const int lp  = idx / 768;
            const int o   = idx - lp * 768;
            const int pos = pbase + lp;
            const int d   = o % 3;
            const int row = 3 * pos + d;
            if (row >= row_base && row < row_base + BM && row < row_end) {
                const int node = spos[pos - pos0];
                out[(size_t)node * (COUT * MM) + Cbase * 3 + o] = ebuf[idx];
            }
        }
    }
}

// ============================================================================
// FALLBACK: exact R9 4-kernel chain (proven 149.9us) — used only if the
// cooperative launch is rejected at capture time.
// ============================================================================
__global__ __launch_bounds__(256)
void prep_kernel(const float* __restrict__ attrs, const float* __restrict__ w,
                 int* __restrict__ species, int* __restrict__ hist,
                 ushort* __restrict__ wt) {
    const int tid = threadIdx.x;
    if (blockIdx.x >= NGRP) {
        const size_t base = (size_t)(blockIdx.x - NGRP) * 2048;
        const float* src = w + base;
        ushort* dst = wt + base;
        float4 a = *(const float4*)(src + tid * 4);
        float4 b = *(const float4*)(src + 1024 + tid * 4);
        uint2 oa, ob;
        oa.x = pack2(a.x, a.y); oa.y = pack2(a.z, a.w);
        ob.x = pack2(b.x, b.y); ob.y = pack2(b.z, b.w);
        *(uint2*)(dst + tid * 4) = oa;
        *(uint2*)(dst + 1024 + tid * 4) = ob;
        return;
    }
    __shared__ int wc[4][NZ];
    const int b = blockIdx.x * 256 + tid;
    const float* a = attrs + (size_t)b * NZ;
    int s = 0;
    #pragma unroll
    for (int z = 0; z < NZ; z++) if (a[z] > 0.5f) s = z;
    species[b] = s;
    const int wv = tid >> 6, lane = tid & 63;
    #pragma unroll
    for (int z = 0; z < NZ; z++) {
        unsigned long long m = __ballot(s == z);
        if (lane == 0) wc[wv][z] = __popcll(m);
    }
    __syncthreads();
    if (tid < NZ)
        hist[blockIdx.x * NZ + tid] = wc[0][tid] + wc[1][tid] + wc[2][tid] + wc[3][tid];
}

__global__ __launch_bounds__(256)
void place_kernel(const int* __restrict__ species, const int* __restrict__ hist,
                  int* __restrict__ sorted, int* __restrict__ offsets,
                  int* __restrict__ tile_offsets) {
    __shared__ int lhist[NGRP][NZ];
    __shared__ int loff[NZ + 1], ltoff[NZ + 1];
    __shared__ int pb[NZ];
    __shared__ int wc[4][NZ];
    const int tid = threadIdx.x, g = blockIdx.x;

    for (int i = tid; i < NGRP * NZ; i += 256) ((int*)lhist)[i] = hist[i];
    __syncthreads();
    if (tid == 0) {
        int off = 0, toff = 0;
        for (int z = 0; z < NZ; z++) {
            int tot = 0;
            for (int gg = 0; gg < NGRP; gg++) tot += lhist[gg][z];
            loff[z] = off; ltoff[z] = toff;
            off += tot;
            toff += (3 * tot + BM - 1) / BM;
        }
        loff[NZ] = off; ltoff[NZ] = toff;
    }
    __syncthreads();
    if (tid < NZ) {
        int base = loff[tid];
        for (int gg = 0; gg < g; gg++) base += lhist[gg][tid];
        pb[tid] = base;
    }
    if (g == 0 && tid < NZ + 1) {
        offsets[tid] = loff[tid];
        tile_offsets[tid] = ltoff[tid];
    }
    const int b = g * 256 + tid;
    const int s = species[b];
    const int wv = tid >> 6, lane = tid & 63;
    unsigned long long mymask = 0;
    #pragma unroll
    for (int z = 0; z < NZ; z++) {
        unsigned long long m = __ballot(s == z);
        if (lane == 0) wc[wv][z] = __popcll(m);
        if (s == z) mymask = m;
    }
    __syncthreads();
    int rank = __popcll(mymask & ((1ull << lane) - 1ull));
    #pragma unroll
    for (int w2 = 0; w2 < 4; w2++) if (w2 < wv) rank += wc[w2][s];
    sorted[pb[s] + rank] = b;
}

__global__ __launch_bounds__(256)
void pack_t(const float* __restrict__ t, const int* __restrict__ sorted,
            ushort* __restrict__ tt) {
    const int w = threadIdx.x >> 6, L = threadIdx.x & 63;
    const int p = blockIdx.x * 4 + w;
    const int node = sorted[p];
    const float4* src = (const float4*)(t + (size_t)node * (CIN * MM) + L * 24);
    float4 f[6];
    #pragma unroll
    for (int i = 0; i < 6; i++) f[i] = src[i];
    const float* v = (const float*)f;
    #pragma unroll
    for (int d = 0; d < MM; d++) {
        uint4 o;
        o.x = pack2(v[d],      v[3 + d]);
        o.y = pack2(v[6 + d],  v[9 + d]);
        o.z = pack2(v[12 + d], v[15 + d]);
        o.w = pack2(v[18 + d], v[21 + d]);
        *(uint4*)&tt[(size_t)(3 * p + d) * CIN + L * 8] = o;
    }
}

__global__ __launch_bounds__(512, 2)
void gemm_kernel(const ushort* __restrict__ tt, const ushort* __restrict__ wt,
                 const int* __restrict__ sorted, const int* __restrict__ offsets,
                 const int* __restrict__ tile_offsets, float* __restrict__ out) {
    extern __shared__ __align__(16) ushort smem[];
    __shared__ int spos[96];

    const int bid = blockIdx.x;
    const int xcd = bid & 7, ii = bid >> 3;
    const int wg = (xcd < 4 ? xcd * 27 : 108 + (xcd - 4) * 26) + ii;
    const int tz = wg >> 1;
    const int Cbase = (wg & 1) * BN;

    if (tz >= tile_offsets[NZ]) return;
    int z = 0;
    #pragma unroll
    for (int i = 1; i < NZ; i++) if (tile_offsets[i] <= tz) z = i;

    const int row_base = 3 * offsets[z] + (tz - tile_offsets[z]) * BM;
    const int row_end  = 3 * offsets[z + 1];
    const int pos0     = row_base / 3;

    const int tid = threadIdx.x;
    const int w = tid >> 6, L = tid & 63;
    if (tid < 96) spos[tid] = sorted[min(pos0 + tid, NB - 1)];

    const int lr16 = w * 16 + (L >> 2);
    const int cs   = (L & 3) ^ ((L >> 3) & 3);
    const size_t aoff = (size_t)(row_base + lr16) * CIN + cs * 8;
    const size_t boff = ((size_t)z * COUT + Cbase + lr16) * CIN + cs * 8;

#define STAGE_A(s, kt) do {                                                   \
        async16(tt + aoff + (kt) * BK, ASLOT(s) + w * 512);                   \
        async16(tt + aoff + (size_t)128 * CIN + (kt) * BK,                    \
                ASLOT(s) + 4096 + w * 512);                                   \
    } while (0)
#define STAGE_B(s, kt) do {                                                   \
        async16(wt + boff + (kt) * BK, BSLOT(s) + w * 512);                   \
        async16(wt + boff + (size_t)128 * CIN + (kt) * BK,                    \
                BSLOT(s) + 4096 + w * 512);                                   \
    } while (0)

    const int wm = w & 1, wn = w >> 1;
    const int q = L >> 4, mr = L & 15;
    const int qs = (q ^ ((mr >> 1) & 3)) * 8;

    f32x4 acc[8][4];
    #pragma unroll
    for (int i = 0; i < 8; i++)
        #pragma unroll
        for (int j = 0; j < 4; j++) acc[i][j] = (f32x4){0.f, 0.f, 0.f, 0.f};

    STAGE_A(0, 0); STAGE_B(0, 0);
    STAGE_A(1, 1); STAGE_B(1, 1);

    int cur = 0, stg = 2;
    for (int kt = 0; kt < NKT; kt++) {
        if (kt + 1 < NKT) {
            asm volatile("s_waitcnt vmcnt(4)" ::: "memory");
        } else {
            asm volatile("s_waitcnt vmcnt(0)" ::: "memory");
        }
        asm volatile("s_barrier" ::: "memory");
        if (kt + 2 < NKT) STAGE_A(stg, kt + 2);

        const ushort* Ab = ASLOT(cur);
        const ushort* Bb = BSLOT(cur);
        bf16x8 af[4], bf[4];
        #pragma unroll
        for (int am = 0; am < 4; am++)
            af[am] = *(const bf16x8*)(Ab + (wm * 128 + am * 16 + mr) * 32 + qs);
        #pragma unroll
        for (int bn = 0; bn < 4; bn++)
            bf[bn] = *(const bf16x8*)(Bb + (wn * 64 + bn * 16 + mr) * 32 + qs);
        __builtin_amdgcn_s_setprio(1);
        #pragma unroll
        for (int am = 0; am < 4; am++)
            #pragma unroll
            for (int bn = 0; bn < 4; bn++)
                acc[am][bn] = __builtin_amdgcn_mfma_f32_16x16x32_bf16(
                    af[am], bf[bn], acc[am][bn], 0, 0, 0);
        __builtin_amdgcn_s_setprio(0);

        asm volatile("s_barrier" ::: "memory");
        if (kt + 2 < NKT) STAGE_B(stg, kt + 2);

        bf16x8 ag[4];
        #pragma unroll
        for (int am = 0; am < 4; am++)
            ag[am] = *(const bf16x8*)(Ab + (wm * 128 + (am + 4) * 16 + mr) * 32 + qs);
        __builtin_amdgcn_s_setprio(1);
        #pragma unroll
        for (int am = 0; am < 4; am++)
            #pragma unroll
            for (int bn = 0; bn < 4; bn++)
                acc[am + 4][bn] = __builtin_amdgcn_mfma_f32_16x16x32_bf16(
                    ag[am], bf[bn], acc[am + 4][bn], 0, 0, 0);
        __builtin_amdgcn_s_setprio(0);

        cur = (cur == 2) ? 0 : cur + 1;
        stg = (stg == 2) ? 0 : stg + 1;
    }
#undef STAGE_A
#undef STAGE_B

    float* ebuf = (float*)smem;
    #pragma unroll
    for (int ch = 0; ch < 6; ch++) {
        __syncthreads();
        const int pbase = pos0 + ch * 16;
        #pragma unroll
        for (int am = 0; am < 8; am++) {
            #pragma unroll
            for (int r = 0; r < 4; r++) {
                const int Rg = row_base + wm * 128 + am * 16 + q * 4 + r;
                const int pos = Rg / 3;
                const int d = Rg - 3 * pos;
                const int lp = pos - pbase;
                if (lp >= 0 && lp < 16 && Rg < row_end) {
                    #pragma unroll
                    for (int bn = 0; bn < 4; bn++) {
                        const int c = wn * 64 + bn * 16 + mr;
                        ebuf[(lp * BN + c) * 3 + d] = ALPHA * acc[am][bn][r];
                    }
                }
            }
        }
        __syncthreads();
        #pragma unroll 4
        for (int j = 0; j < 24; j++) {
            const int idx = j * 512 + tid;
            const int lp  = idx / 768;
            const int o   = idx - lp * 768;
            const int pos = pbase + lp;
            const int d   = o % 3;
            const int row = 3 * pos + d;
            if (row >= row_base && row < row_base + BM && row < row_end) {
                const int node = spos[pos - pos0];
                out[(size_t)node * (COUT * MM) + Cbase * 3 + o] = ebuf[idx];
            }
        }
    }
}

extern "C" void kernel_launch(void* const* d_in, const int* in_sizes, int n_in,
                              void* d_out, int out_size, void* d_ws, size_t ws_size,
                              hipStream_t stream) {
    const float* t     = (const float*)d_in[0];   // [B, IN, 3]  fp32
    const float* attrs = (const float*)d_in[1];   // [B, Z]      fp32 one-hot
    const float* w     = (const float*)d_in[2];   // [Z, OUT, IN] fp32
    float* out = (float*)d_out;                   // [B, OUT, 3] fp32

    uint8_t* ws = (uint8_t*)d_ws;
    int* species      = (int*)ws;                  ws += NB * 4;
    int* sorted       = (int*)ws;                  ws += NB * 4;
    int* hist         = (int*)ws;                  ws += NGRP * NZ * 4;
    int* offsets      = (int*)ws;                  ws += 16 * 4;
    int* tile_offsets = (int*)ws;                  ws += 16 * 4;
    int* meta         = (int*)ws;                  ws += 32 * 4;
    ws = (uint8_t*)(((uintptr_t)ws + 255) & ~(uintptr_t)255);
    ushort* wt  = (ushort*)ws;                     ws += (size_t)NZ * COUT * CIN * 2;
    ushort* ttn = (ushort*)ws;                     // 24576 rows x CIN bf16

    // zero cnt/cursor each replay (graph-capturable; the harness's own
    // reset() uses hipMemsetAsync)
    hipMemsetAsync(meta, 0, 32 * 4, stream);

    hipFuncSetAttribute((const void*)fused_kernel,
                        hipFuncAttributeMaxDynamicSharedMemorySize, DYN_LDS);

    void* args[] = {(void*)&t, (void*)&attrs, (void*)&w, (void*)&out,
                    (void*)&sorted, (void*)&meta, (void*)&wt, (void*)&ttn};
    hipError_t e = hipLaunchCooperativeKernel((const void*)fused_kernel,
                                              dim3(NWG), dim3(512), args,
                                              DYN_LDS, stream);
    if (e != hipSuccess) {
        // fallback: proven R9 4-kernel chain (node-order buffer reused as tt)
        hipLaunchKernelGGL(prep_kernel, dim3(NGRP + (NZ * COUT * CIN) / 2048),
                           dim3(256), 0, stream, attrs, w, species, hist, wt);
        hipLaunchKernelGGL(place_kernel, dim3(NGRP), dim3(256), 0, stream,
                           species, hist, sorted, offsets, tile_offsets);
        hipLaunchKernelGGL(pack_t, dim3(NB / 4), dim3(256), 0, stream,
                           t, sorted, ttn);
        hipLaunchKernelGGL(gemm_kernel, dim3(NWG), dim3(512), DYN_LDS, stream,
                           ttn, wt, sorted, offsets, tile_offsets, out);
    }
}